// Round 1
// baseline (80.007 us; speedup 1.0000x reference)
//
#include <hip/hip_runtime.h>
#include <math.h>

#define B_DIM 4096
#define L_DIM 512
#define N_DIM 1024

// -½·log(2): the value of each term once P has fully underflowed to zero.
#define NEG_HALF_LOG2 (-0.34657359027997264f)

// ---------------------------------------------------------------------------
// Kernel A: transpose eps (2, N, L) -> epsT (L, 2, N) so per-step reads are
// contiguous in n. Standard 32x32 LDS tile transpose, both sides coalesced.
// ---------------------------------------------------------------------------
__global__ void transpose_eps(const float* __restrict__ eps,
                              float* __restrict__ epsT) {
    __shared__ float tile[32][33];
    const int s  = blockIdx.z;
    const int i0 = blockIdx.x * 32;   // i tile base (L dim)
    const int n0 = blockIdx.y * 32;   // n tile base (N dim)
    const int tx = threadIdx.x;       // 0..31  (i on read, n on write)
    const int ty = threadIdx.y;       // 0..7
#pragma unroll
    for (int k = 0; k < 32; k += 8) {
        // read coalesced along i (innermost of source)
        tile[ty + k][tx] =
            eps[((size_t)s * N_DIM + (size_t)(n0 + ty + k)) * L_DIM + (i0 + tx)];
    }
    __syncthreads();
#pragma unroll
    for (int k = 0; k < 32; k += 8) {
        // write coalesced along n (innermost of dest)
        epsT[(size_t)(i0 + ty + k) * (2 * N_DIM) + (size_t)s * N_DIM + (n0 + tx)] =
            tile[tx][ty + k];
    }
}

// ---------------------------------------------------------------------------
// Kernel B: main recurrence. One 64-lane wave per row b. Lane owns 16 n's
// (4 chunks of float4, chunk c covers n = c*256 + lane*4 .. +3) of the
// running product P in VGPRs. Per step: load eps slices for s=0/1, two dot
// products (butterfly-reduced over the wave), accumulate the normalized
// picked log-amplitude, update P, and vote on all-P-zero for early exit.
// ---------------------------------------------------------------------------
template <bool USE_T>
__global__ __launch_bounds__(512, 4) void arqgps_main(
    const int* __restrict__ indices,
    const float* __restrict__ eps,    // original (2,N,L) layout (fallback path)
    const float* __restrict__ epsT,   // transposed (L,2,N) layout
    float* __restrict__ out)
{
    const int lane = threadIdx.x & 63;
    const int wave = __builtin_amdgcn_readfirstlane((int)(threadIdx.x >> 6));
    const int b    = blockIdx.x * 8 + wave;

    const int* idx_row = indices + (size_t)b * L_DIM;

    float P[4][4];
#pragma unroll
    for (int c = 0; c < 4; ++c)
#pragma unroll
        for (int j = 0; j < 4; ++j) P[c][j] = 1.0f;

    float acc = 0.0f;

    for (int i = 0; i < L_DIM; ++i) {
        float4 e0v[4], e1v[4];
        if (USE_T) {
            const float* e = epsT + (size_t)i * (2 * N_DIM);
#pragma unroll
            for (int c = 0; c < 4; ++c) {
                e0v[c] = *(const float4*)(e + c * 256 + lane * 4);
                e1v[c] = *(const float4*)(e + N_DIM + c * 256 + lane * 4);
            }
        } else {
#pragma unroll
            for (int c = 0; c < 4; ++c) {
                const int n = c * 256 + lane * 4;
                float* p0 = (float*)&e0v[c];
                float* p1 = (float*)&e1v[c];
#pragma unroll
                for (int j = 0; j < 4; ++j) {
                    p0[j] = eps[(size_t)(n + j) * L_DIM + i];
                    p1[j] = eps[((size_t)N_DIM + (n + j)) * L_DIM + i];
                }
            }
        }

        // Two dot products against P.
        float x0 = 0.0f, x1 = 0.0f;
#pragma unroll
        for (int c = 0; c < 4; ++c) {
            const float* f0 = (const float*)&e0v[c];
            const float* f1 = (const float*)&e1v[c];
#pragma unroll
            for (int j = 0; j < 4; ++j) {
                x0 = fmaf(f0[j], P[c][j], x0);
                x1 = fmaf(f1[j], P[c][j], x1);
            }
        }
        // Butterfly reduce across all 64 lanes (every lane gets the sums).
#pragma unroll
        for (int off = 32; off >= 1; off >>= 1) {
            x0 += __shfl_xor(x0, off, 64);
            x1 += __shfl_xor(x1, off, 64);
        }

        const int s_i = idx_row[i];   // uniform per wave -> one cached load
        const float xs = s_i ? x1 : x0;
        const float m  = fmaxf(x0, x1);
        const float d  = fabsf(x0 - x1);
        // picked - ½·logsumexp(2x0,2x1) = xs - m - ½·log(1 + exp(-2d))
        acc += xs - m - 0.5f * log1pf(__expf(-2.0f * d));

        // Update running product P *= eps[s_i, n, i]; track any-nonzero.
        unsigned nz = 0u;
#pragma unroll
        for (int c = 0; c < 4; ++c) {
            const float* f0 = (const float*)&e0v[c];
            const float* f1 = (const float*)&e1v[c];
#pragma unroll
            for (int j = 0; j < 4; ++j) {
                const float es = s_i ? f1[j] : f0[j];
                P[c][j] *= es;
                // shift out the sign bit: nonzero magnitude iff (u<<1) != 0
                nz |= (__float_as_uint(P[c][j]) << 1);
            }
        }
        if (!__any(nz != 0u)) {
            // All P are exactly zero -> every remaining step contributes
            // exactly -½·log2 (x0 = x1 = 0).
            acc += (float)(L_DIM - 1 - i) * NEG_HALF_LOG2;
            break;
        }
    }

    if (lane == 0) out[b] = acc;
}

extern "C" void kernel_launch(void* const* d_in, const int* in_sizes, int n_in,
                              void* d_out, int out_size, void* d_ws, size_t ws_size,
                              hipStream_t stream) {
    const int*   indices = (const int*)d_in[0];
    const float* eps     = (const float*)d_in[1];
    float*       out     = (float*)d_out;

    const size_t need = (size_t)2 * N_DIM * L_DIM * sizeof(float);  // 4 MB
    if (ws_size >= need) {
        float* epsT = (float*)d_ws;
        dim3 tgrid(L_DIM / 32, N_DIM / 32, 2);   // (16, 32, 2)
        transpose_eps<<<tgrid, dim3(32, 8), 0, stream>>>(eps, epsT);
        arqgps_main<true><<<B_DIM / 8, 512, 0, stream>>>(indices, eps, epsT, out);
    } else {
        // Fallback: read eps in-place (strided, slower, still correct).
        arqgps_main<false><<<B_DIM / 8, 512, 0, stream>>>(indices, eps, nullptr, out);
    }
}

// Round 3
// 55.444 us; speedup vs baseline: 1.4430x; 1.4430x over previous
//
#include <hip/hip_runtime.h>
#include <math.h>

#define B_DIM 4096
#define L_DIM 512
#define N_DIM 1024

// -half*log(2): exact value of each term once P has fully underflowed to zero.
#define NEG_HALF_LOG2 (-0.34657359027997264f)

// ---------------------------------------------------------------------------
// Kernel A: transpose eps (2, N, L) -> epsT (L, 2, N) so per-step reads are
// contiguous in n. Standard 32x32 LDS tile transpose, both sides coalesced.
// ---------------------------------------------------------------------------
__global__ void transpose_eps(const float* __restrict__ eps,
                              float* __restrict__ epsT) {
    __shared__ float tile[32][33];
    const int s  = blockIdx.z;
    const int i0 = blockIdx.x * 32;   // i tile base (L dim)
    const int n0 = blockIdx.y * 32;   // n tile base (N dim)
    const int tx = threadIdx.x;       // 0..31
    const int ty = threadIdx.y;       // 0..7
#pragma unroll
    for (int k = 0; k < 32; k += 8) {
        tile[ty + k][tx] =
            eps[((size_t)s * N_DIM + (size_t)(n0 + ty + k)) * L_DIM + (i0 + tx)];
    }
    __syncthreads();
#pragma unroll
    for (int k = 0; k < 32; k += 8) {
        epsT[(size_t)(i0 + ty + k) * (2 * N_DIM) + (size_t)s * N_DIM + (n0 + tx)] =
            tile[tx][ty + k];
    }
}

// ---------------------------------------------------------------------------
// DPP wave-64 sum. dpp_ctrl must be a compile-time constant -> template arg.
// After the sequence, lane 63 holds the full 64-lane sum:
//   row_shr 1/2/4/8  -> lane 15 of each row-of-16 holds its row sum
//   row_bcast:15     -> lane 31 += row0 sum, lane 47 += row1.., lane 63 += row2..
//   row_bcast:31     -> lane 63 += lane31's partial
// All VALU-pipe (no LDS), ~6-op dependent chain.
// ---------------------------------------------------------------------------
template <int CTRL>
__device__ __forceinline__ float dpp_add(float x) {
    int v = __builtin_amdgcn_update_dpp(0, __float_as_int(x), CTRL, 0xf, 0xf, true);
    return x + __int_as_float(v);
}
__device__ __forceinline__ float wave_sum63(float x) {
    x = dpp_add<0x111>(x);  // row_shr:1
    x = dpp_add<0x112>(x);  // row_shr:2
    x = dpp_add<0x114>(x);  // row_shr:4
    x = dpp_add<0x118>(x);  // row_shr:8
    x = dpp_add<0x142>(x);  // row_bcast:15
    x = dpp_add<0x143>(x);  // row_bcast:31
    return x;
}
__device__ __forceinline__ float read63(float x) {
    return __int_as_float(__builtin_amdgcn_readlane(__float_as_int(x), 63));
}

// ---------------------------------------------------------------------------
// Kernel B: one 64-lane wave per row b. Lane owns 16 n's (4 x float4 chunks)
// of the running product P in VGPRs. Per step: load both eps slices, two dot
// products (DPP-reduced, read from lane 63), uniform tail math, P *= selected
// slice under a wave-uniform scalar branch. All-zero early-exit check every
// 4 steps (overshoot is exact: post-zero terms are exactly -1/2*log2).
// ---------------------------------------------------------------------------
template <bool USE_T>
__global__ __launch_bounds__(512, 4) void arqgps_main(
    const int* __restrict__ indices,
    const float* __restrict__ eps,    // original (2,N,L) layout (fallback)
    const float* __restrict__ epsT,   // transposed (L,2,N) layout
    float* __restrict__ out)
{
    const int lane = threadIdx.x & 63;
    const int wave = threadIdx.x >> 6;
    const int b    = blockIdx.x * 8 + wave;
    const int* idx_row = indices + (size_t)b * L_DIM;

    float P[16];
#pragma unroll
    for (int j = 0; j < 16; ++j) P[j] = 1.0f;
    float acc = 0.0f;

    for (int i0 = 0; i0 < L_DIM; i0 += 4) {
        // one uniform 16B load of this chunk's 4 indices
        const int4 sidx = *(const int4*)(idx_row + i0);
#pragma unroll
        for (int k = 0; k < 4; ++k) {
            const int i = i0 + k;
            float e0[16], e1[16];
            if (USE_T) {
                const float* e = epsT + (size_t)i * (2 * N_DIM);
#pragma unroll
                for (int c = 0; c < 4; ++c) {
                    const float4 v0 = *(const float4*)(e + c * 256 + lane * 4);
                    const float4 v1 = *(const float4*)(e + N_DIM + c * 256 + lane * 4);
                    e0[4 * c + 0] = v0.x; e0[4 * c + 1] = v0.y;
                    e0[4 * c + 2] = v0.z; e0[4 * c + 3] = v0.w;
                    e1[4 * c + 0] = v1.x; e1[4 * c + 1] = v1.y;
                    e1[4 * c + 2] = v1.z; e1[4 * c + 3] = v1.w;
                }
            } else {
#pragma unroll
                for (int c = 0; c < 4; ++c) {
                    const int n = c * 256 + lane * 4;
#pragma unroll
                    for (int j = 0; j < 4; ++j) {
                        e0[4 * c + j] = eps[(size_t)(n + j) * L_DIM + i];
                        e1[4 * c + j] = eps[((size_t)N_DIM + (n + j)) * L_DIM + i];
                    }
                }
            }

            // Two dot products against P (split accumulators for ILP).
            float a0 = 0.f, a1 = 0.f, b0 = 0.f, b1 = 0.f;
#pragma unroll
            for (int j = 0; j < 16; j += 2) {
                a0 = fmaf(e0[j],     P[j],     a0);
                a1 = fmaf(e0[j + 1], P[j + 1], a1);
                b0 = fmaf(e1[j],     P[j],     b0);
                b1 = fmaf(e1[j + 1], P[j + 1], b1);
            }
            const float X0 = read63(wave_sum63(a0 + a1));
            const float X1 = read63(wave_sum63(b0 + b1));

            const int k_si = (k == 0) ? sidx.x : (k == 1) ? sidx.y
                           : (k == 2) ? sidx.z : sidx.w;
            const int s_i  = __builtin_amdgcn_readfirstlane(k_si);

            // acc += picked - 1/2 * logsumexp(2*X0, 2*X1)
            const float xs = s_i ? X1 : X0;
            const float m  = fmaxf(X0, X1);
            const float d  = fabsf(X0 - X1);
            const float t  = __expf(-2.0f * d);
            acc += (xs - m) - 0.5f * __logf(1.0f + t);

            // P *= eps[s_i, n, i] under a wave-uniform scalar branch.
            if (s_i) {
#pragma unroll
                for (int j = 0; j < 16; ++j) P[j] *= e1[j];
            } else {
#pragma unroll
                for (int j = 0; j < 16; ++j) P[j] *= e0[j];
            }
        }

        // All-|P| max via max-tree (abs input mods are free on consumers).
        float m0 = fmaxf(fmaxf(fabsf(P[0]),  fabsf(P[1])),  fabsf(P[2]));
        float m1 = fmaxf(fmaxf(fabsf(P[3]),  fabsf(P[4])),  fabsf(P[5]));
        float m2 = fmaxf(fmaxf(fabsf(P[6]),  fabsf(P[7])),  fabsf(P[8]));
        float m3 = fmaxf(fmaxf(fabsf(P[9]),  fabsf(P[10])), fabsf(P[11]));
        float m4 = fmaxf(fmaxf(fabsf(P[12]), fabsf(P[13])), fabsf(P[14]));
        float mx = fmaxf(fmaxf(fmaxf(m0, m1), fmaxf(m2, m3)),
                         fmaxf(m4, fabsf(P[15])));
        if (!__any(mx > 0.0f)) {
            // Every remaining step contributes exactly -1/2*log2.
            acc += (float)(L_DIM - 4 - i0) * NEG_HALF_LOG2;
            break;
        }
    }

    if (lane == 0) out[b] = acc;
}

extern "C" void kernel_launch(void* const* d_in, const int* in_sizes, int n_in,
                              void* d_out, int out_size, void* d_ws, size_t ws_size,
                              hipStream_t stream) {
    const int*   indices = (const int*)d_in[0];
    const float* eps     = (const float*)d_in[1];
    float*       out     = (float*)d_out;

    const size_t need = (size_t)2 * N_DIM * L_DIM * sizeof(float);  // 4 MB
    if (ws_size >= need) {
        float* epsT = (float*)d_ws;
        dim3 tgrid(L_DIM / 32, N_DIM / 32, 2);
        transpose_eps<<<tgrid, dim3(32, 8), 0, stream>>>(eps, epsT);
        arqgps_main<true><<<B_DIM / 8, 512, 0, stream>>>(indices, eps, epsT, out);
    } else {
        arqgps_main<false><<<B_DIM / 8, 512, 0, stream>>>(indices, eps, nullptr, out);
    }
}